// Round 3
// baseline (3068.395 us; speedup 1.0000x reference)
//
#include <hip/hip_runtime.h>

// VGAE encoder: 3x GCNConv (sym-norm + self loops), relu, relu, none.
// out = concat(mu, logstd=mu)
constexpr int NN = 50000;   // nodes
constexpr int NE = 800000;  // edges

// ---- degree / dinv ---------------------------------------------------------
__global__ void k_deg(const int* __restrict__ dst, float* __restrict__ deg) {
    int e = blockIdx.x * blockDim.x + threadIdx.x;
    if (e < NE) unsafeAtomicAdd(&deg[dst[e]], 1.0f);
}

__global__ void k_dinv(float* __restrict__ deg) {
    int n = blockIdx.x * blockDim.x + threadIdx.x;
    if (n < NN) deg[n] = rsqrtf(deg[n] + 1.0f);  // +1 self loop
}

// ---- dense h = X @ W  (W staged in LDS, 1 thread per output element) ------
template<int FIN, int FOUT>
__global__ void k_gemm(const float* __restrict__ X, const float* __restrict__ W,
                       float* __restrict__ H) {
    __shared__ float sW[FIN * FOUT];
    constexpr int BLK = FOUT * 4;  // 4 rows per block
    for (int i = threadIdx.x; i < FIN * FOUT; i += BLK) sW[i] = W[i];
    __syncthreads();
    int row = blockIdx.x * 4 + threadIdx.x / FOUT;
    int col = threadIdx.x % FOUT;
    if (row >= NN) return;
    const float* xr = X + (size_t)row * FIN;
    float acc = 0.f;
#pragma unroll
    for (int k = 0; k < FIN; ++k) acc += xr[k] * sW[k * FOUT + col];
    H[(size_t)row * FOUT + col] = acc;
}

// ---- agg init with self-loop term: agg = dinv[n]^2 * h[n] ------------------
template<int F>
__global__ void k_self(const float* __restrict__ H, const float* __restrict__ dinv,
                       float* __restrict__ agg) {
    int idx = blockIdx.x * blockDim.x + threadIdx.x;
    if (idx < NN * F) {
        int n = idx / F;
        float di = dinv[n];
        agg[idx] = di * di * H[idx];
    }
}

// ---- edge scatter: agg[dst] += h[src] * dinv[src]*dinv[dst] ----------------
template<int F>
__global__ void k_edge(const int* __restrict__ src, const int* __restrict__ dst,
                       const float* __restrict__ H, const float* __restrict__ dinv,
                       float* __restrict__ agg) {
    constexpr int C = F / 4;  // float4 chunks per edge
    int tid = blockIdx.x * blockDim.x + threadIdx.x;
    int e = tid / C;
    int c = tid % C;
    if (e >= NE) return;
    int s = src[e], d = dst[e];
    float coef = dinv[s] * dinv[d];
    float4 v = *(const float4*)(H + (size_t)s * F + c * 4);
    float* ap = agg + (size_t)d * F + c * 4;
    unsafeAtomicAdd(ap + 0, v.x * coef);
    unsafeAtomicAdd(ap + 1, v.y * coef);
    unsafeAtomicAdd(ap + 2, v.z * coef);
    unsafeAtomicAdd(ap + 3, v.w * coef);
}

// ---- bias (+relu), in place ------------------------------------------------
template<int F, bool RELU>
__global__ void k_bias(float* __restrict__ agg, const float* __restrict__ b) {
    int idx = blockIdx.x * blockDim.x + threadIdx.x;
    if (idx < NN * F) {
        float v = agg[idx] + b[idx % F];
        agg[idx] = RELU ? fmaxf(v, 0.f) : v;
    }
}

// ---- final: mu = agg + b2; logstd = mu (mirror into second half) -----------
__global__ void k_final(float* __restrict__ out, const float* __restrict__ b) {
    constexpr int T = NN * 64;
    int idx = blockIdx.x * blockDim.x + threadIdx.x;
    if (idx < T) {
        float v = out[idx] + b[idx & 63];
        out[idx] = v;
        out[T + idx] = v;
    }
}

extern "C" void kernel_launch(void* const* d_in, const int* in_sizes, int n_in,
                              void* d_out, int out_size, void* d_ws, size_t ws_size,
                              hipStream_t stream) {
    const float* x  = (const float*)d_in[0];
    const int*   ei = (const int*)d_in[1];  // [2, NE] int32
    const float* W0 = (const float*)d_in[2];
    const float* b0 = (const float*)d_in[3];
    const float* W1 = (const float*)d_in[4];
    const float* b1 = (const float*)d_in[5];
    const float* W2 = (const float*)d_in[6];
    const float* b2 = (const float*)d_in[7];
    float* out = (float*)d_out;

    float* ws   = (float*)d_ws;
    float* dinv = ws;                    // NN floats (padded to 51200)
    float* bufH = ws + 51200;            // NN*96
    float* bufA = bufH + (size_t)NN * 96; // NN*96

    const int* src = ei;
    const int* dst = ei + NE;

    // degrees -> dinv
    hipMemsetAsync(dinv, 0, NN * sizeof(float), stream);
    k_deg<<<(NE + 255) / 256, 256, 0, stream>>>(dst, dinv);
    k_dinv<<<(NN + 255) / 256, 256, 0, stream>>>(dinv);

    constexpr int G96 = (NN * 96 + 255) / 256;
    constexpr int G64 = (NN * 64 + 255) / 256;

    // layer 0: x -> bufA (relu)
    k_gemm<96, 96><<<12500, 384, 0, stream>>>(x, W0, bufH);
    k_self<96><<<G96, 256, 0, stream>>>(bufH, dinv, bufA);
    k_edge<96><<<NE * 24 / 256, 256, 0, stream>>>(src, dst, bufH, dinv, bufA);
    k_bias<96, true><<<G96, 256, 0, stream>>>(bufA, b0);

    // layer 1: bufA -> bufA (relu); agg overwrites input after gemm consumed it
    k_gemm<96, 96><<<12500, 384, 0, stream>>>(bufA, W1, bufH);
    k_self<96><<<G96, 256, 0, stream>>>(bufH, dinv, bufA);
    k_edge<96><<<NE * 24 / 256, 256, 0, stream>>>(src, dst, bufH, dinv, bufA);
    k_bias<96, true><<<G96, 256, 0, stream>>>(bufA, b1);

    // layer 2: bufA -> out[0:NN*64] (mu), then mirror to logstd
    k_gemm<96, 64><<<12500, 256, 0, stream>>>(bufA, W2, bufH);
    k_self<64><<<G64, 256, 0, stream>>>(bufH, dinv, out);
    k_edge<64><<<NE * 16 / 256, 256, 0, stream>>>(src, dst, bufH, dinv, out);
    k_final<<<G64, 256, 0, stream>>>(out, b2);
}

// Round 4
// 448.655 us; speedup vs baseline: 6.8391x; 6.8391x over previous
//
#include <hip/hip_runtime.h>

// VGAE encoder: 3x GCNConv (sym-norm + self loops), relu, relu, none.
// out = concat(mu, logstd=mu)
// Round 4: replace fp32 atomic scatter (1.2 GB HBM write-through per layer!)
// with CSR build + gather aggregation. Fuse self-loop+bias+relu into gather.
constexpr int NN = 50000;   // nodes
constexpr int NE = 800000;  // edges

// ---- CSR build: count in-degree at dst -------------------------------------
__global__ void k_count(const int* __restrict__ dst, int* __restrict__ cnt) {
    int e = blockIdx.x * blockDim.x + threadIdx.x;
    if (e < NE) atomicAdd(&cnt[dst[e]], 1);
}

// ---- single-block exclusive scan of counts -> rowptr, cursor; also dinv ----
__global__ void __launch_bounds__(1024) k_scan(const int* __restrict__ cnt,
                                               int* __restrict__ rowptr,
                                               int* __restrict__ cursor,
                                               float* __restrict__ dinv) {
    __shared__ int wexcl[16];
    __shared__ int s_carry;
    __shared__ int s_total;
    int tid = threadIdx.x;
    int lane = tid & 63, wid = tid >> 6;
    if (tid == 0) s_carry = 0;
    __syncthreads();
    for (int base = 0; base < NN; base += 1024) {
        int i = base + tid;
        int v = (i < NN) ? cnt[i] : 0;
        int x = v;  // wave-inclusive scan
#pragma unroll
        for (int off = 1; off < 64; off <<= 1) {
            int t = __shfl_up(x, off);
            if (lane >= off) x += t;
        }
        if (lane == 63) wexcl[wid] = x;  // wave totals
        __syncthreads();
        int carry = s_carry;
        if (wid == 0) {
            int wt = (lane < 16) ? wexcl[lane] : 0;
            int y = wt;
#pragma unroll
            for (int off = 1; off < 16; off <<= 1) {
                int t = __shfl_up(y, off);
                if (lane >= off) y += t;
            }
            if (lane < 16) wexcl[lane] = y - wt;  // exclusive wave offsets
            if (lane == 15) s_total = y;          // tile total
        }
        __syncthreads();
        if (i < NN) {
            int r = carry + wexcl[wid] + (x - v);  // global exclusive prefix
            rowptr[i] = r;
            cursor[i] = r;
            dinv[i] = rsqrtf((float)v + 1.0f);  // +1 self loop
        }
        __syncthreads();
        if (tid == 0) s_carry = carry + s_total;
        __syncthreads();
    }
    if (tid == 0) rowptr[NN] = s_carry;
}

// ---- fill CSR with (src, coef) pairs ---------------------------------------
__global__ void k_fill(const int* __restrict__ src, const int* __restrict__ dst,
                       const float* __restrict__ dinv, int* __restrict__ cursor,
                       int2* __restrict__ pairs) {
    int e = blockIdx.x * blockDim.x + threadIdx.x;
    if (e >= NE) return;
    int s = src[e], d = dst[e];
    int pos = atomicAdd(&cursor[d], 1);
    float coef = dinv[s] * dinv[d];
    pairs[pos] = make_int2(s, __float_as_int(coef));
}

// ---- dense H = X @ W, LDS-staged, float4 per thread ------------------------
template<int FIN, int FOUT, int ROWS>
__global__ void k_gemm(const float* __restrict__ X, const float* __restrict__ W,
                       float* __restrict__ H) {
    constexpr int G = FOUT / 4;         // float4 cols
    constexpr int NT = ROWS * G;        // threads per block
    __shared__ float sW[FIN * FOUT];
    __shared__ float sX[ROWS * FIN];
    int tid = threadIdx.x;
    int row0 = blockIdx.x * ROWS;
    for (int i = tid; i < FIN * FOUT / 4; i += NT)
        ((float4*)sW)[i] = ((const float4*)W)[i];
    for (int i = tid; i < ROWS * FIN / 4; i += NT) {
        int r = i / (FIN / 4);
        ((float4*)sX)[i] = ((const float4*)(X + (size_t)(row0 + r) * FIN))[i % (FIN / 4)];
    }
    __syncthreads();
    int r = tid / G, g = tid % G;
    float4 acc = make_float4(0.f, 0.f, 0.f, 0.f);
#pragma unroll
    for (int k = 0; k < FIN; ++k) {
        float xv = sX[r * FIN + k];
        float4 w4 = ((const float4*)sW)[k * G + g];
        acc.x += xv * w4.x; acc.y += xv * w4.y;
        acc.z += xv * w4.z; acc.w += xv * w4.w;
    }
    ((float4*)H)[(size_t)(row0 + r) * G + g] = acc;
}

// ---- gather aggregate + self-loop + bias (+relu | mirror) ------------------
// MODE 0: relu, write outp.  MODE 1: no relu, write outp and outp+NN*F (mirror).
template<int F, int MODE>
__global__ void k_agg(const float* __restrict__ H, const int* __restrict__ rowptr,
                      const int2* __restrict__ pairs, const float* __restrict__ dinv,
                      const float* __restrict__ b, float* __restrict__ outp) {
    constexpr int C = F / 4;
    int tid = blockIdx.x * blockDim.x + threadIdx.x;
    int n = tid / C, c = tid % C;
    if (n >= NN) return;
    int beg = rowptr[n], end = rowptr[n + 1];
    float di = dinv[n];
    const float4* h4 = (const float4*)H;
    float4 hv = h4[(size_t)n * C + c];
    float sl = di * di;
    float4 acc = make_float4(sl * hv.x, sl * hv.y, sl * hv.z, sl * hv.w);
    for (int p = beg; p < end; ++p) {
        int2 pr = pairs[p];
        float coef = __int_as_float(pr.y);
        float4 v = h4[(size_t)pr.x * C + c];
        acc.x += coef * v.x; acc.y += coef * v.y;
        acc.z += coef * v.z; acc.w += coef * v.w;
    }
    float4 bb = *(const float4*)(b + c * 4);
    acc.x += bb.x; acc.y += bb.y; acc.z += bb.z; acc.w += bb.w;
    if (MODE == 0) {
        acc.x = fmaxf(acc.x, 0.f); acc.y = fmaxf(acc.y, 0.f);
        acc.z = fmaxf(acc.z, 0.f); acc.w = fmaxf(acc.w, 0.f);
        ((float4*)outp)[(size_t)n * C + c] = acc;
    } else {
        ((float4*)outp)[(size_t)n * C + c] = acc;
        ((float4*)outp)[(size_t)NN * C + (size_t)n * C + c] = acc;  // logstd = mu
    }
}

extern "C" void kernel_launch(void* const* d_in, const int* in_sizes, int n_in,
                              void* d_out, int out_size, void* d_ws, size_t ws_size,
                              hipStream_t stream) {
    const float* x  = (const float*)d_in[0];
    const int*   ei = (const int*)d_in[1];  // [2, NE] int32
    const float* W0 = (const float*)d_in[2];
    const float* b0 = (const float*)d_in[3];
    const float* W1 = (const float*)d_in[4];
    const float* b1 = (const float*)d_in[5];
    const float* W2 = (const float*)d_in[6];
    const float* b2 = (const float*)d_in[7];
    float* out = (float*)d_out;

    // ws layout (floats/ints, all 16B-aligned): [cnt 51200][rowptr 51200]
    // [cursor 51200][dinv 51200][pairs 1.6M words][bufH 4.8M][bufA 4.8M] = 45.6 MB
    int*   cnt    = (int*)d_ws;
    int*   rowptr = cnt + 51200;
    int*   cursor = rowptr + 51200;
    float* dinv   = (float*)(cursor + 51200);
    int2*  pairs  = (int2*)(dinv + 51200);
    float* bufH   = (float*)(pairs + NE);
    float* bufA   = bufH + (size_t)NN * 96;

    const int* src = ei;
    const int* dst = ei + NE;

    // CSR build (graph constant across layers; rebuilt identically every call)
    hipMemsetAsync(cnt, 0, NN * sizeof(int), stream);
    k_count<<<NE / 256, 256, 0, stream>>>(dst, cnt);
    k_scan<<<1, 1024, 0, stream>>>(cnt, rowptr, cursor, dinv);
    k_fill<<<NE / 256, 256, 0, stream>>>(src, dst, dinv, cursor, pairs);

    constexpr int AG96 = (NN * 24 + 255) / 256;  // 4688
    constexpr int AG64 = NN * 16 / 256;          // 3125

    // layer 0: x -> bufA (relu)
    k_gemm<96, 96, 8><<<NN / 8, 192, 0, stream>>>(x, W0, bufH);
    k_agg<96, 0><<<AG96, 256, 0, stream>>>(bufH, rowptr, pairs, dinv, b0, bufA);
    // layer 1: bufA -> bufA (relu)
    k_gemm<96, 96, 8><<<NN / 8, 192, 0, stream>>>(bufA, W1, bufH);
    k_agg<96, 0><<<AG96, 256, 0, stream>>>(bufH, rowptr, pairs, dinv, b1, bufA);
    // layer 2: bufA -> out (mu, mirrored to logstd)
    k_gemm<96, 64, 16><<<NN / 16, 256, 0, stream>>>(bufA, W2, bufH);
    k_agg<64, 1><<<AG64, 256, 0, stream>>>(bufH, rowptr, pairs, dinv, b2, out);
}